// Round 4
// baseline (205.987 us; speedup 1.0000x reference)
//
#include <hip/hip_runtime.h>
#include <hip/hip_bf16.h>
#include <stdint.h>

// ---------------------------------------------------------------------------
// TrigramWriteMemoryAttention  (B=2, T=1024, D=1024, H=16, dh=64, pd=4)
// ---------------------------------------------------------------------------

typedef __attribute__((ext_vector_type(8))) __bf16 bf16v8;
typedef __attribute__((ext_vector_type(8))) short  s16x8;
typedef __attribute__((ext_vector_type(4))) float  f32x4;

#define LOG2E 1.4426950408889634f

__device__ __forceinline__ float bf2f(short s) {
  union { uint32_t u; float f; } cv; cv.u = ((uint32_t)(uint16_t)s) << 16; return cv.f;
}
__device__ __forceinline__ short f2bf(float f) {
  union { float f; uint32_t u; } cv; cv.f = f;
  uint32_t r = cv.u + 0x7fffu + ((cv.u >> 16) & 1u);
  return (short)(r >> 16);
}

__device__ __forceinline__ f32x4 mfma_bf16(s16x8 a, s16x8 b, f32x4 c) {
  return __builtin_amdgcn_mfma_f32_16x16x32_bf16(
      __builtin_bit_cast(bf16v8, a), __builtin_bit_cast(bf16v8, b), c, 0, 0, 0);
}

__device__ __forceinline__ void gload_lds16(const void* g, void* l) {
  __builtin_amdgcn_global_load_lds(
      (const __attribute__((address_space(1))) uint32_t*)g,
      (__attribute__((address_space(3))) uint32_t*)l, 16, 0, 0);
}

// ---------------- conversions ----------------

__global__ void k_cvt(const float* __restrict__ in, short* __restrict__ out, int n) {
  int i = (blockIdx.x * 256 + threadIdx.x) * 4;
  if (i < n) {
    float4 v = *(const float4*)&in[i];
    short4 o;
    o.x = f2bf(v.x); o.y = f2bf(v.y); o.z = f2bf(v.z); o.w = f2bf(v.w);
    *(short4*)&out[i] = o;
  }
}

// W[K][N] f32 -> Wt[N][K] bf16   (K,N multiples of 32)
__global__ void k_tconv(const float* __restrict__ W, short* __restrict__ Wt, int K, int N) {
  __shared__ float tile[32][33];
  const int n0 = blockIdx.x * 32, k0 = blockIdx.y * 32;
  const int tx = threadIdx.x, ty = threadIdx.y;  // blockDim 32x8
#pragma unroll
  for (int i = 0; i < 4; i++)
    tile[ty + i * 8][tx] = W[(size_t)(k0 + ty + i * 8) * N + n0 + tx];
  __syncthreads();
#pragma unroll
  for (int i = 0; i < 4; i++)
    Wt[(size_t)(n0 + ty + i * 8) * K + k0 + tx] = f2bf(tile[tx][ty + i * 8]);
}

// Build smallwT [384][1024] bf16 (see row map in k_lines comment)
__global__ void k_smallw(const float* __restrict__ w1w, const float* __restrict__ w2w,
                         const float* __restrict__ r1w, const float* __restrict__ r2w,
                         const float* __restrict__ gw, short* __restrict__ out) {
  const int idx = blockIdx.x * 256 + threadIdx.x;  // 384*1024
  const int r = idx >> 10, k = idx & 1023;
  float v = 0.f;
  if (r < 64)       v = w1w[(size_t)k * 64 + r];
  else if (r < 128) v = w1w[(size_t)(1024 + k) * 64 + (r - 64)];
  else if (r < 192) v = w2w[(size_t)k * 64 + (r - 128)];
  else if (r < 256) v = r1w[(size_t)k * 64 + (r - 192)];
  else if (r < 320) v = r2w[(size_t)k * 64 + (r - 256)];
  else if (r < 336) v = gw[(size_t)k * 16 + (r - 320)];
  out[idx] = f2bf(v);
}

// ---------------- GEMM: C[M,N] = A[M,K] @ Bt[N,K]^T (+bias) ----------------

template <bool OUTBF>
__global__ __launch_bounds__(256) void k_gemm(const short* __restrict__ A,
                                              const short* __restrict__ Bt,
                                              void* __restrict__ Cp,
                                              const float* __restrict__ bias,
                                              int N, int K) {
  __shared__ short As[128 * 32];
  __shared__ short Bs[128 * 32];
  const int m0 = blockIdx.x * 128, n0 = blockIdx.y * 128;
  const int tid = threadIdx.x;
  const int lane = tid & 63, w = tid >> 6;
  const int wr = (w >> 1) * 64, wc = (w & 1) * 64;
  const int l15 = lane & 15, lg = lane >> 4;
  f32x4 acc[4][4] = {};
  for (int k0 = 0; k0 < K; k0 += 32) {
#pragma unroll
    for (int p = 0; p < 2; p++) {
      const int e = p * 256 + tid;
      const int r = e >> 2, c8 = (e & 3) << 3;
      gload_lds16(A + (size_t)(m0 + r) * K + k0 + c8, As + e * 8);
      gload_lds16(Bt + (size_t)(n0 + r) * K + k0 + c8, Bs + e * 8);
    }
    __syncthreads();
    s16x8 af[4], bfv[4];
#pragma unroll
    for (int i = 0; i < 4; i++) {
      af[i]  = *(const s16x8*)&As[(wr + i * 16 + l15) * 32 + lg * 8];
      bfv[i] = *(const s16x8*)&Bs[(wc + i * 16 + l15) * 32 + lg * 8];
    }
#pragma unroll
    for (int mi = 0; mi < 4; mi++)
#pragma unroll
      for (int ni = 0; ni < 4; ni++)
        acc[mi][ni] = mfma_bf16(af[mi], bfv[ni], acc[mi][ni]);
    __syncthreads();
  }
#pragma unroll
  for (int mi = 0; mi < 4; mi++)
#pragma unroll
    for (int ni = 0; ni < 4; ni++) {
      const int col = n0 + wc + ni * 16 + l15;
      const float bv = bias ? bias[col] : 0.f;
#pragma unroll
      for (int r = 0; r < 4; r++) {
        const int row = m0 + wr + mi * 16 + lg * 4 + r;
        const float v = acc[mi][ni][r] + bv;
        if (OUTBF) ((short*)Cp)[(size_t)row * N + col] = f2bf(v);
        else       ((float*)Cp)[(size_t)row * N + col] = v;
      }
    }
}

// ---------------- flash attention ----------------
// Grid 1024 = 32 bh x 32 q-tiles of 32 rows, XCD-swizzled (all q-tiles of a
// head stay on one XCD -> K/V L2-resident).  128 threads = 2 waves, wave w
// owns 16 q-rows.  KV tiles of 64; single-buffered LDS with reg-prefetch
// (T14): issue next tile's global loads before compute, LDS-write after the
// post-compute barrier.  ~23 KB LDS -> 6 blocks/CU -> 3 waves/SIMD.

__global__ __launch_bounds__(128, 3) void k_attn(const short* __restrict__ qkv,
                                                 short* __restrict__ outp) {
  const int id = blockIdx.x;
  const int xcd = id & 7, idx = id >> 3;
  const int bh = xcd + 8 * (idx >> 5);   // 0..31
  const int qt = idx & 31;               // 0..31
  const int b = bh >> 4, h = bh & 15;
  const int tid = threadIdx.x, lane = tid & 63, w = tid >> 6;
  const int l15 = lane & 15, lg = lane >> 4;
  const int q0 = qt * 32;
  const int nkv = (qt >> 1) + 1;

  __shared__ short Kl[64 * 72];
  __shared__ short Vt[64 * 72];        // V^T: [dh][s]
  __shared__ short Pl[2][16 * 72];     // wave-private P
  const short* base = qkv + (size_t)b * 1024 * 3072;
  short* op = outp + (size_t)b * 1024 * 1024;

  // K staging: p in 0..3, unit e = p*128+tid -> row e>>3, col8 (e&7)*8
  // V staging: s = tid&63, d-base (tid>>6)*8 + p*16  (column scalar writes)
  const int vs = tid & 63;
  const int vdb = (tid >> 6) * 8;

  s16x8 qf[2];
#pragma unroll
  for (int ks = 0; ks < 2; ks++)
    qf[ks] = *(const s16x8*)&base[(size_t)(q0 + w * 16 + l15) * 3072 +
                                  h * 64 + ks * 32 + lg * 8];

  f32x4 O[4] = {};
  float m_run[4], l_run[4];
#pragma unroll
  for (int r = 0; r < 4; r++) { m_run[r] = -1e30f; l_run[r] = 0.f; }

  s16x8 kpre[4], vpre[4];
  // stage tile 0
#pragma unroll
  for (int p = 0; p < 4; p++) {
    const int e = p * 128 + tid;
    kpre[p] = *(const s16x8*)&base[(size_t)(e >> 3) * 3072 + 1024 + h * 64 + ((e & 7) << 3)];
    vpre[p] = *(const s16x8*)&base[(size_t)vs * 3072 + 2048 + h * 64 + vdb + p * 16];
  }
#pragma unroll
  for (int p = 0; p < 4; p++) {
    const int e = p * 128 + tid;
    *(s16x8*)&Kl[(e >> 3) * 72 + ((e & 7) << 3)] = kpre[p];
#pragma unroll
    for (int j = 0; j < 8; j++) Vt[(vdb + p * 16 + j) * 72 + vs] = vpre[p][j];
  }
  __syncthreads();

  for (int kt = 0; kt < nkv; kt++) {
    const int kv0 = kt * 64;
    const bool pf = (kt + 1 < nkv);
    if (pf) {
      const int kvn = kv0 + 64;
#pragma unroll
      for (int p = 0; p < 4; p++) {
        const int e = p * 128 + tid;
        kpre[p] = *(const s16x8*)&base[(size_t)(kvn + (e >> 3)) * 3072 + 1024 + h * 64 + ((e & 7) << 3)];
        vpre[p] = *(const s16x8*)&base[(size_t)(kvn + vs) * 3072 + 2048 + h * 64 + vdb + p * 16];
      }
    }

    // S = Q @ K^T
    f32x4 S[4] = {};
    __builtin_amdgcn_s_setprio(1);
#pragma unroll
    for (int sf = 0; sf < 4; sf++) {
      s16x8 kf0 = *(const s16x8*)&Kl[(sf * 16 + l15) * 72 + lg * 8];
      s16x8 kf1 = *(const s16x8*)&Kl[(sf * 16 + l15) * 72 + 32 + lg * 8];
      S[sf] = mfma_bf16(qf[0], kf0, S[sf]);
      S[sf] = mfma_bf16(qf[1], kf1, S[sf]);
    }
    __builtin_amdgcn_s_setprio(0);

    const bool diag = (kt == nkv - 1);
    float sv[4][4];
#pragma unroll
    for (int sf = 0; sf < 4; sf++)
#pragma unroll
      for (int r = 0; r < 4; r++) {
        float v = S[sf][r] * 0.125f;
        if (diag) {
          const int sg = kv0 + sf * 16 + l15;
          const int qg = q0 + w * 16 + lg * 4 + r;
          if (sg > qg) v = -1e30f;
        }
        sv[sf][r] = v;
      }
#pragma unroll
    for (int r = 0; r < 4; r++) {
      float pm = fmaxf(fmaxf(sv[0][r], sv[1][r]), fmaxf(sv[2][r], sv[3][r]));
      pm = fmaxf(pm, __shfl_xor(pm, 1, 64));
      pm = fmaxf(pm, __shfl_xor(pm, 2, 64));
      pm = fmaxf(pm, __shfl_xor(pm, 4, 64));
      pm = fmaxf(pm, __shfl_xor(pm, 8, 64));
      const float mn = fmaxf(m_run[r], pm);
      const float fac = exp2f((m_run[r] - mn) * LOG2E);
      m_run[r] = mn;
      float rs = 0.f;
#pragma unroll
      for (int sf = 0; sf < 4; sf++) {
        float p = (sv[sf][r] <= -1e29f) ? 0.f : exp2f((sv[sf][r] - mn) * LOG2E);
        rs += p;
        Pl[w][(lg * 4 + r) * 72 + sf * 16 + l15] = f2bf(p);
      }
      rs += __shfl_xor(rs, 1, 64);
      rs += __shfl_xor(rs, 2, 64);
      rs += __shfl_xor(rs, 4, 64);
      rs += __shfl_xor(rs, 8, 64);
      l_run[r] = l_run[r] * fac + rs;
#pragma unroll
      for (int nf = 0; nf < 4; nf++) O[nf][r] *= fac;
    }

    // O += P @ V
    __builtin_amdgcn_s_setprio(1);
#pragma unroll
    for (int ks = 0; ks < 2; ks++) {
      s16x8 pfr = *(const s16x8*)&Pl[w][l15 * 72 + ks * 32 + lg * 8];
#pragma unroll
      for (int nf = 0; nf < 4; nf++) {
        s16x8 vf = *(const s16x8*)&Vt[(nf * 16 + l15) * 72 + ks * 32 + lg * 8];
        O[nf] = mfma_bf16(pfr, vf, O[nf]);
      }
    }
    __builtin_amdgcn_s_setprio(0);

    __syncthreads();
    if (pf) {
#pragma unroll
      for (int p = 0; p < 4; p++) {
        const int e = p * 128 + tid;
        *(s16x8*)&Kl[(e >> 3) * 72 + ((e & 7) << 3)] = kpre[p];
#pragma unroll
        for (int j = 0; j < 8; j++) Vt[(vdb + p * 16 + j) * 72 + vs] = vpre[p][j];
      }
      __syncthreads();
    }
  }

#pragma unroll
  for (int nf = 0; nf < 4; nf++)
#pragma unroll
    for (int r = 0; r < 4; r++) {
      const int row = q0 + w * 16 + lg * 4 + r;
      op[(size_t)row * 1024 + h * 64 + nf * 16 + l15] = f2bf(O[nf][r] / l_run[r]);
    }
}

// ---------------- Plucker lines ----------------

__device__ __forceinline__ void exterior6(const float p1[4], const float p2[4], float L[6]) {
  L[0] = p1[0] * p2[1] - p1[1] * p2[0];
  L[1] = p1[0] * p2[2] - p1[2] * p2[0];
  L[2] = p1[0] * p2[3] - p1[3] * p2[0];
  L[3] = p1[1] * p2[2] - p1[2] * p2[1];
  L[4] = p1[1] * p2[3] - p1[3] * p2[1];
  L[5] = p1[2] * p2[3] - p1[3] * p2[2];
  float n = sqrtf(L[0] * L[0] + L[1] * L[1] + L[2] * L[2] +
                  L[3] * L[3] + L[4] * L[4] + L[5] * L[5]);
  float inv = 1.f / fmaxf(n, 1e-12f);
#pragma unroll
  for (int j = 0; j < 6; j++) L[j] *= inv;
}

// proj [2048][384]: cols 0:64 xw1a, 64:128 xw1b, 128:192 w2, 192:256 r1,
// 256:320 r2, 320:336 gate_pre.
// jw layout: SoA [bh][6][1024]; rl layout: AoS [bh][t][6]
__global__ void k_lines(const float* __restrict__ proj, const float* __restrict__ Jm,
                        float* __restrict__ jw, float* __restrict__ rl) {
  const int idx = blockIdx.x * 256 + threadIdx.x;  // 32768
  const int t = idx & 1023, h = (idx >> 10) & 15, b = idx >> 14;
  const int n = b * 1024 + t;
  const int bh = b * 16 + h;
  float p1[4], p2[4], L[6];
#pragma unroll
  for (int p = 0; p < 4; p++) {
    float a  = (t >= 2) ? proj[(size_t)(n - 2) * 384 + h * 4 + p] : 0.f;
    float bb = (t >= 1) ? proj[(size_t)(n - 1) * 384 + 64 + h * 4 + p] : 0.f;
    p1[p] = a + bb;
    p2[p] = proj[(size_t)n * 384 + 128 + h * 4 + p];
  }
  exterior6(p1, p2, L);
  const size_t jo = (size_t)bh * 6144 + t;
#pragma unroll
  for (int j = 0; j < 6; j++) {
    float s = 0.f;
#pragma unroll
    for (int i = 0; i < 6; i++) s += L[i] * Jm[i * 6 + j];
    jw[jo + (size_t)j * 1024] = s;
  }
#pragma unroll
  for (int p = 0; p < 4; p++) {
    p1[p] = proj[(size_t)n * 384 + 192 + h * 4 + p];
    p2[p] = proj[(size_t)n * 384 + 256 + h * 4 + p];
  }
  exterior6(p1, p2, L);
  const size_t ro = ((size_t)bh * 1024 + t) * 6;
#pragma unroll
  for (int j = 0; j < 6; j++) rl[ro + j] = L[j];
}

// ---------------- decayed memory score ----------------
// One wave per (b,h,t): lane handles s = lane, lane+64, ...

__global__ __launch_bounds__(256) void k_mscore(const float* __restrict__ jw,
                                                const float* __restrict__ rl,
                                                const float* __restrict__ dlog,
                                                float* __restrict__ ms) {
  const int gtid = blockIdx.x * 256 + threadIdx.x;
  const int wid = gtid >> 6, lane = gtid & 63;
  const int bh = wid >> 10, t = wid & 1023;
  const int h = bh & 15, b = bh >> 4;
  const float d = 1.f / (1.f + expf(-dlog[h]));
  const float l2d = log2f(d);
  const float* jwp = jw + (size_t)bh * 6144;
  const float* rp = rl + ((size_t)bh * 1024 + t) * 6;
  const float r0 = rp[0], r1 = rp[1], r2 = rp[2], r3 = rp[3], r4 = rp[4], r5 = rp[5];
  float wgt = exp2f((float)(t - lane) * l2d);   // d^(t-lane)
  const float gw = exp2f(-64.f * l2d);          // d^-64 per stride step
  float acc = 0.f;
  for (int s = lane; s < t; s += 64) {
    const float dot = r0 * jwp[s] + r1 * jwp[1024 + s] + r2 * jwp[2048 + s] +
                      r3 * jwp[3072 + s] + r4 * jwp[4096 + s] + r5 * jwp[5120 + s];
    acc += wgt * dot * dot;
    wgt *= gw;
  }
  acc += __shfl_xor(acc, 1, 64);
  acc += __shfl_xor(acc, 2, 64);
  acc += __shfl_xor(acc, 4, 64);
  acc += __shfl_xor(acc, 8, 64);
  acc += __shfl_xor(acc, 16, 64);
  acc += __shfl_xor(acc, 32, 64);
  if (lane == 0) ms[((size_t)(b * 1024 + t)) * 16 + h] = acc;
}

// ---------------- combine: comb = bf16(attn + gated*mem_val) ----------------

__global__ __launch_bounds__(256) void k_combine(const short* __restrict__ attn,
                                                 const short* __restrict__ mv,
                                                 const float* __restrict__ proj,
                                                 const float* __restrict__ ms,
                                                 const float* __restrict__ mem_scale,
                                                 const float* __restrict__ gate_b,
                                                 short* __restrict__ comb) {
  const int n = blockIdx.x;
  const int tid = threadIdx.x;
  __shared__ float gsh;
  if (tid < 16) {
    const float gp = proj[(size_t)n * 384 + 320 + tid] + gate_b[tid];
    const float g = 1.f / (1.f + expf(-gp));
    const float sc = ms[(size_t)n * 16 + tid] * mem_scale[tid];
    const float sg = 1.f / (1.f + expf(-sc));
    float v = sg * g;
    v += __shfl_xor(v, 1, 64);
    v += __shfl_xor(v, 2, 64);
    v += __shfl_xor(v, 4, 64);
    v += __shfl_xor(v, 8, 64);
    if (tid == 0) gsh = v * (1.f / 16.f);
  }
  __syncthreads();
  const float g = gsh;
  const int c0 = tid * 4;
  short4 av = *(const short4*)&attn[(size_t)n * 1024 + c0];
  short4 mvv = *(const short4*)&mv[(size_t)n * 1024 + c0];
  short4 ov;
  ov.x = f2bf(bf2f(av.x) + g * bf2f(mvv.x));
  ov.y = f2bf(bf2f(av.y) + g * bf2f(mvv.y));
  ov.z = f2bf(bf2f(av.z) + g * bf2f(mvv.z));
  ov.w = f2bf(bf2f(av.w) + g * bf2f(mvv.w));
  *(short4*)&comb[(size_t)n * 1024 + c0] = ov;
}

// ---------------------------------------------------------------------------

extern "C" void kernel_launch(void* const* d_in, const int* in_sizes, int n_in,
                              void* d_out, int out_size, void* d_ws, size_t ws_size,
                              hipStream_t stream) {
  const float* x    = (const float*)d_in[0];
  const float* qkvw = (const float*)d_in[1];
  const float* qkvb = (const float*)d_in[2];
  const float* w1w  = (const float*)d_in[3];
  const float* w2w  = (const float*)d_in[4];
  const float* r1w  = (const float*)d_in[5];
  const float* r2w  = (const float*)d_in[6];
  const float* mvw  = (const float*)d_in[7];
  const float* mvb  = (const float*)d_in[8];
  const float* gw   = (const float*)d_in[9];
  const float* gb   = (const float*)d_in[10];
  const float* msc  = (const float*)d_in[11];
  const float* ow   = (const float*)d_in[12];
  const float* ob   = (const float*)d_in[13];
  const float* dlog = (const float*)d_in[14];
  const float* Jm   = (const float*)d_in[15];
  float* out = (float*)d_out;

  char* wsp = (char*)d_ws;
  auto alloc = [&](size_t bytes) {
    char* p = wsp;
    wsp += (bytes + 255) & ~(size_t)255;
    return p;
  };
  short* xb    = (short*)alloc((size_t)2048 * 1024 * 2);
  short* qkvwT = (short*)alloc((size_t)3072 * 1024 * 2);
  short* mvwT  = (short*)alloc((size_t)1024 * 1024 * 2);
  short* owT   = (short*)alloc((size_t)1024 * 1024 * 2);
  short* smwT  = (short*)alloc((size_t)384 * 1024 * 2);
  short* qkvo  = (short*)alloc((size_t)2048 * 3072 * 2);
  float* proj  = (float*)alloc((size_t)2048 * 384 * 4);
  short* attnO = (short*)alloc((size_t)2048 * 1024 * 2);
  short* memv  = (short*)alloc((size_t)2048 * 1024 * 2);
  float* jwb   = (float*)alloc((size_t)32 * 6144 * 4);
  float* rlb   = (float*)alloc((size_t)32768 * 6 * 4);
  float* msb   = (float*)alloc((size_t)2048 * 16 * 4);
  short* comb  = qkvo;  // reuse: qkv dead after attention

  k_cvt<<<2048, 256, 0, stream>>>(x, xb, 2048 * 1024);
  dim3 tb(32, 8);
  k_tconv<<<dim3(96, 32), tb, 0, stream>>>(qkvw, qkvwT, 1024, 3072);
  k_tconv<<<dim3(32, 32), tb, 0, stream>>>(mvw, mvwT, 1024, 1024);
  k_tconv<<<dim3(32, 32), tb, 0, stream>>>(ow, owT, 1024, 1024);
  k_smallw<<<1536, 256, 0, stream>>>(w1w, w2w, r1w, r2w, gw, smwT);

  k_gemm<true><<<dim3(16, 24), 256, 0, stream>>>(xb, qkvwT, qkvo, qkvb, 3072, 1024);
  k_gemm<false><<<dim3(16, 3), 256, 0, stream>>>(xb, smwT, proj, (const float*)nullptr, 384, 1024);
  k_gemm<true><<<dim3(16, 8), 256, 0, stream>>>(xb, mvwT, memv, mvb, 1024, 1024);

  k_attn<<<1024, 128, 0, stream>>>(qkvo, attnO);
  k_lines<<<128, 256, 0, stream>>>(proj, Jm, jwb, rlb);
  k_mscore<<<8192, 256, 0, stream>>>(jwb, rlb, dlog, msb);
  k_combine<<<2048, 256, 0, stream>>>(attnO, memv, proj, msb, msc, gb, comb);

  k_gemm<false><<<dim3(16, 8), 256, 0, stream>>>(comb, owT, out, ob, 1024, 1024);
}

// Round 5
// 156.391 us; speedup vs baseline: 1.3171x; 1.3171x over previous
//
#include <hip/hip_runtime.h>
#include <hip/hip_bf16.h>
#include <stdint.h>

// ---------------------------------------------------------------------------
// TrigramWriteMemoryAttention  (B=2, T=1024, D=1024, H=16, dh=64, pd=4)
// Fused buffer layout (bf16, row stride 4480):
//   cols 0:1024 Q | 1024:2048 K | 2048:3072 V | 3072:4096 mem_val | 4096:4480 small
// small cols (also written f32 to projf[2048][384]):
//   0:64 xw1a | 64:128 xw1b | 128:192 w2 | 192:256 r1 | 256:320 r2 | 320:336 gate
// ---------------------------------------------------------------------------

typedef __attribute__((ext_vector_type(8))) __bf16 bf16v8;
typedef __attribute__((ext_vector_type(8))) short  s16x8;
typedef __attribute__((ext_vector_type(4))) float  f32x4;

#define LOG2E 1.4426950408889634f

__device__ __forceinline__ float bf2f(short s) {
  union { uint32_t u; float f; } cv; cv.u = ((uint32_t)(uint16_t)s) << 16; return cv.f;
}
__device__ __forceinline__ short f2bf(float f) {
  union { float f; uint32_t u; } cv; cv.f = f;
  uint32_t r = cv.u + 0x7fffu + ((cv.u >> 16) & 1u);
  return (short)(r >> 16);
}

__device__ __forceinline__ f32x4 mfma_bf16(s16x8 a, s16x8 b, f32x4 c) {
  return __builtin_amdgcn_mfma_f32_16x16x32_bf16(
      __builtin_bit_cast(bf16v8, a), __builtin_bit_cast(bf16v8, b), c, 0, 0, 0);
}

__device__ __forceinline__ void gload_lds16(const void* g, void* l) {
  __builtin_amdgcn_global_load_lds(
      (const __attribute__((address_space(1))) uint32_t*)g,
      (__attribute__((address_space(3))) uint32_t*)l, 16, 0, 0);
}

// ---------------- conversions ----------------

__global__ void k_cvt(const float* __restrict__ in, short* __restrict__ out, int n) {
  int i = (blockIdx.x * 256 + threadIdx.x) * 4;
  if (i < n) {
    float4 v = *(const float4*)&in[i];
    short4 o;
    o.x = f2bf(v.x); o.y = f2bf(v.y); o.z = f2bf(v.z); o.w = f2bf(v.w);
    *(short4*)&out[i] = o;
  }
}

// W[K][N] f32 -> Wt[N][K] bf16   (K,N multiples of 32)
__global__ void k_tconv(const float* __restrict__ W, short* __restrict__ Wt, int K, int N) {
  __shared__ float tile[32][33];
  const int n0 = blockIdx.x * 32, k0 = blockIdx.y * 32;
  const int tx = threadIdx.x, ty = threadIdx.y;  // blockDim 32x8
#pragma unroll
  for (int i = 0; i < 4; i++)
    tile[ty + i * 8][tx] = W[(size_t)(k0 + ty + i * 8) * N + n0 + tx];
  __syncthreads();
#pragma unroll
  for (int i = 0; i < 4; i++)
    Wt[(size_t)(n0 + ty + i * 8) * K + k0 + tx] = f2bf(tile[tx][ty + i * 8]);
}

// Build smallwT rows of btall[4096:4480][1024] bf16, plus biasAll[4480] f32.
__global__ void k_smallw(const float* __restrict__ w1w, const float* __restrict__ w2w,
                         const float* __restrict__ r1w, const float* __restrict__ r2w,
                         const float* __restrict__ gw, const float* __restrict__ qkvb,
                         const float* __restrict__ mvb, short* __restrict__ out,
                         float* __restrict__ biasAll) {
  if (blockIdx.x >= 1536) {  // bias region
    const int i = (blockIdx.x - 1536) * 256 + threadIdx.x;
    if (i < 4480) {
      float v = 0.f;
      if (i < 3072) v = qkvb[i];
      else if (i < 4096) v = mvb[i - 3072];
      biasAll[i] = v;
    }
    return;
  }
  const int idx = blockIdx.x * 256 + threadIdx.x;  // 384*1024
  const int r = idx >> 10, k = idx & 1023;
  float v = 0.f;
  if (r < 64)       v = w1w[(size_t)k * 64 + r];
  else if (r < 128) v = w1w[(size_t)(1024 + k) * 64 + (r - 64)];
  else if (r < 192) v = w2w[(size_t)k * 64 + (r - 128)];
  else if (r < 256) v = r1w[(size_t)k * 64 + (r - 192)];
  else if (r < 320) v = r2w[(size_t)k * 64 + (r - 256)];
  else if (r < 336) v = gw[(size_t)k * 16 + (r - 320)];
  out[idx] = f2bf(v);
}

// ---------------- fused projection GEMM ----------------
// C[2048][4480] = xb @ btall^T + biasAll; proj cols (>=4096) go to projf f32.

__global__ __launch_bounds__(256) void k_gemmF(const short* __restrict__ A,
                                               const short* __restrict__ Bt,
                                               short* __restrict__ C,
                                               const float* __restrict__ bias,
                                               float* __restrict__ projf) {
  const int N = 4480, K = 1024;
  __shared__ short As[128 * 32];
  __shared__ short Bs[128 * 32];
  const int m0 = blockIdx.x * 128, n0 = blockIdx.y * 128;
  const int tid = threadIdx.x;
  const int lane = tid & 63, w = tid >> 6;
  const int wr = (w >> 1) * 64, wc = (w & 1) * 64;
  const int l15 = lane & 15, lg = lane >> 4;
  f32x4 acc[4][4] = {};
  for (int k0 = 0; k0 < K; k0 += 32) {
#pragma unroll
    for (int p = 0; p < 2; p++) {
      const int e = p * 256 + tid;
      const int r = e >> 2, c8 = (e & 3) << 3;
      gload_lds16(A + (size_t)(m0 + r) * K + k0 + c8, As + e * 8);
      gload_lds16(Bt + (size_t)(n0 + r) * K + k0 + c8, Bs + e * 8);
    }
    __syncthreads();
    s16x8 af[4], bfv[4];
#pragma unroll
    for (int i = 0; i < 4; i++) {
      af[i]  = *(const s16x8*)&As[(wr + i * 16 + l15) * 32 + lg * 8];
      bfv[i] = *(const s16x8*)&Bs[(wc + i * 16 + l15) * 32 + lg * 8];
    }
#pragma unroll
    for (int mi = 0; mi < 4; mi++)
#pragma unroll
      for (int ni = 0; ni < 4; ni++)
        acc[mi][ni] = mfma_bf16(af[mi], bfv[ni], acc[mi][ni]);
    __syncthreads();
  }
  const bool isproj = (n0 >= 4096);
#pragma unroll
  for (int mi = 0; mi < 4; mi++)
#pragma unroll
    for (int ni = 0; ni < 4; ni++) {
      const int col = n0 + wc + ni * 16 + l15;
      const float bv = bias[col];
#pragma unroll
      for (int r = 0; r < 4; r++) {
        const int row = m0 + wr + mi * 16 + lg * 4 + r;
        const float v = acc[mi][ni][r] + bv;
        if (isproj) projf[(size_t)row * 384 + (col - 4096)] = v;
        else        C[(size_t)row * 4480 + col] = f2bf(v);
      }
    }
}

// ---------------- generic GEMM (out-projection) ----------------

__global__ __launch_bounds__(256) void k_gemm(const short* __restrict__ A,
                                              const short* __restrict__ Bt,
                                              float* __restrict__ C,
                                              const float* __restrict__ bias,
                                              int N, int K) {
  __shared__ short As[128 * 32];
  __shared__ short Bs[128 * 32];
  const int m0 = blockIdx.x * 128, n0 = blockIdx.y * 128;
  const int tid = threadIdx.x;
  const int lane = tid & 63, w = tid >> 6;
  const int wr = (w >> 1) * 64, wc = (w & 1) * 64;
  const int l15 = lane & 15, lg = lane >> 4;
  f32x4 acc[4][4] = {};
  for (int k0 = 0; k0 < K; k0 += 32) {
#pragma unroll
    for (int p = 0; p < 2; p++) {
      const int e = p * 256 + tid;
      const int r = e >> 2, c8 = (e & 3) << 3;
      gload_lds16(A + (size_t)(m0 + r) * K + k0 + c8, As + e * 8);
      gload_lds16(Bt + (size_t)(n0 + r) * K + k0 + c8, Bs + e * 8);
    }
    __syncthreads();
    s16x8 af[4], bfv[4];
#pragma unroll
    for (int i = 0; i < 4; i++) {
      af[i]  = *(const s16x8*)&As[(wr + i * 16 + l15) * 32 + lg * 8];
      bfv[i] = *(const s16x8*)&Bs[(wc + i * 16 + l15) * 32 + lg * 8];
    }
#pragma unroll
    for (int mi = 0; mi < 4; mi++)
#pragma unroll
      for (int ni = 0; ni < 4; ni++)
        acc[mi][ni] = mfma_bf16(af[mi], bfv[ni], acc[mi][ni]);
    __syncthreads();
  }
#pragma unroll
  for (int mi = 0; mi < 4; mi++)
#pragma unroll
    for (int ni = 0; ni < 4; ni++) {
      const int col = n0 + wc + ni * 16 + l15;
      const float bv = bias ? bias[col] : 0.f;
#pragma unroll
      for (int r = 0; r < 4; r++) {
        const int row = m0 + wr + mi * 16 + lg * 4 + r;
        C[(size_t)row * N + col] = acc[mi][ni][r] + bv;
      }
    }
}

// ---------------- V transpose: fused V cols -> vtg[bh][64][1024] ----------------

__global__ void k_vtr(const short* __restrict__ fused, short* __restrict__ vtg) {
  __shared__ short tile[32][33];
  const int bh = blockIdx.z;
  const int b = bh >> 4, h = bh & 15;
  const int t0 = blockIdx.x * 32, d0 = blockIdx.y * 32;
  const int tx = threadIdx.x, ty = threadIdx.y;  // 32x8
#pragma unroll
  for (int i = 0; i < 4; i++)
    tile[ty + i * 8][tx] =
        fused[(size_t)(b * 1024 + t0 + ty + i * 8) * 4480 + 2048 + h * 64 + d0 + tx];
  __syncthreads();
#pragma unroll
  for (int i = 0; i < 4; i++)
    vtg[(size_t)(bh * 64 + d0 + ty + i * 8) * 1024 + t0 + tx] = tile[tx][ty + i * 8];
}

// ---------------- flash attention ----------------
// 512 blocks (2 waves each): bh = (n&7) + 8*((n>>3)&3), pair = n>>5.
// Block does q-tiles {pair, 31-pair} (32 rows each) -> uniform 17 kv-tiles.
// All pairs of a head on one XCD (K/V L2-resident).  K and V^T both staged
// as b128 loads/writes; reg-prefetch (T14) overlaps next tile with compute.

__global__ __launch_bounds__(128) void k_attn(const short* __restrict__ fused,
                                              const short* __restrict__ vtg,
                                              short* __restrict__ outp) {
  const int n = blockIdx.x;
  const int pair = n >> 5;
  const int bh = (n & 7) + 8 * ((n >> 3) & 3);
  const int b = bh >> 4, h = bh & 15;
  const int tid = threadIdx.x, lane = tid & 63, w = tid >> 6;
  const int l15 = lane & 15, lg = lane >> 4;
  __shared__ short Kl[64 * 72];
  __shared__ short Vt[64 * 72];        // V^T: [dh][s]
  __shared__ short Pl[2][16 * 72];     // wave-private P
  const short* base = fused + (size_t)b * 1024 * 4480;
  const short* vbase = vtg + (size_t)bh * 64 * 1024;
  short* op = outp + (size_t)b * 1024 * 1024;

  for (int half = 0; half < 2; half++) {
    const int qt = half ? (31 - pair) : pair;
    const int q0 = qt * 32;
    const int nkv = (qt >> 1) + 1;

    s16x8 qf[2];
#pragma unroll
    for (int ks = 0; ks < 2; ks++)
      qf[ks] = *(const s16x8*)&base[(size_t)(q0 + w * 16 + l15) * 4480 +
                                    h * 64 + ks * 32 + lg * 8];

    f32x4 O[4] = {};
    float m_run[4], l_run[4];
#pragma unroll
    for (int r = 0; r < 4; r++) { m_run[r] = -1e30f; l_run[r] = 0.f; }

    s16x8 kpre[4], vpre[4];
#pragma unroll
    for (int p = 0; p < 4; p++) {
      const int e = p * 128 + tid;
      kpre[p] = *(const s16x8*)&base[(size_t)(e >> 3) * 4480 + 1024 + h * 64 + ((e & 7) << 3)];
      vpre[p] = *(const s16x8*)&vbase[(size_t)(e >> 3) * 1024 + ((e & 7) << 3)];
    }
#pragma unroll
    for (int p = 0; p < 4; p++) {
      const int e = p * 128 + tid;
      *(s16x8*)&Kl[(e >> 3) * 72 + ((e & 7) << 3)] = kpre[p];
      *(s16x8*)&Vt[(e >> 3) * 72 + ((e & 7) << 3)] = vpre[p];
    }
    __syncthreads();

    for (int kt = 0; kt < nkv; kt++) {
      const int kv0 = kt * 64;
      const bool pf = (kt + 1 < nkv);
      s16x8 kn[4], vn[4];
      if (pf) {
        const int kvn = kv0 + 64;
#pragma unroll
        for (int p = 0; p < 4; p++) {
          const int e = p * 128 + tid;
          kn[p] = *(const s16x8*)&base[(size_t)(kvn + (e >> 3)) * 4480 + 1024 + h * 64 + ((e & 7) << 3)];
          vn[p] = *(const s16x8*)&vbase[(size_t)(e >> 3) * 1024 + kvn + ((e & 7) << 3)];
        }
      }

      // S = Q @ K^T
      f32x4 S[4] = {};
      __builtin_amdgcn_s_setprio(1);
#pragma unroll
      for (int sf = 0; sf < 4; sf++) {
        s16x8 kf0 = *(const s16x8*)&Kl[(sf * 16 + l15) * 72 + lg * 8];
        s16x8 kf1 = *(const s16x8*)&Kl[(sf * 16 + l15) * 72 + 32 + lg * 8];
        S[sf] = mfma_bf16(qf[0], kf0, S[sf]);
        S[sf] = mfma_bf16(qf[1], kf1, S[sf]);
      }
      __builtin_amdgcn_s_setprio(0);

      const bool diag = (kt == nkv - 1);
      float sv[4][4];
#pragma unroll
      for (int sf = 0; sf < 4; sf++)
#pragma unroll
        for (int r = 0; r < 4; r++) {
          float v = S[sf][r] * 0.125f;
          if (diag) {
            const int sg = kv0 + sf * 16 + l15;
            const int qg = q0 + w * 16 + lg * 4 + r;
            if (sg > qg) v = -1e30f;
          }
          sv[sf][r] = v;
        }
#pragma unroll
      for (int r = 0; r < 4; r++) {
        float pm = fmaxf(fmaxf(sv[0][r], sv[1][r]), fmaxf(sv[2][r], sv[3][r]));
        pm = fmaxf(pm, __shfl_xor(pm, 1, 64));
        pm = fmaxf(pm, __shfl_xor(pm, 2, 64));
        pm = fmaxf(pm, __shfl_xor(pm, 4, 64));
        pm = fmaxf(pm, __shfl_xor(pm, 8, 64));
        const float mn = fmaxf(m_run[r], pm);
        const float fac = exp2f((m_run[r] - mn) * LOG2E);
        m_run[r] = mn;
        float rs = 0.f;
#pragma unroll
        for (int sf = 0; sf < 4; sf++) {
          float p = (sv[sf][r] <= -1e29f) ? 0.f : exp2f((sv[sf][r] - mn) * LOG2E);
          rs += p;
          Pl[w][(lg * 4 + r) * 72 + sf * 16 + l15] = f2bf(p);
        }
        rs += __shfl_xor(rs, 1, 64);
        rs += __shfl_xor(rs, 2, 64);
        rs += __shfl_xor(rs, 4, 64);
        rs += __shfl_xor(rs, 8, 64);
        l_run[r] = l_run[r] * fac + rs;
#pragma unroll
        for (int nf = 0; nf < 4; nf++) O[nf][r] *= fac;
      }

      // O += P @ V
      __builtin_amdgcn_s_setprio(1);
#pragma unroll
      for (int ks = 0; ks < 2; ks++) {
        s16x8 pfr = *(const s16x8*)&Pl[w][l15 * 72 + ks * 32 + lg * 8];
#pragma unroll
        for (int nf = 0; nf < 4; nf++) {
          s16x8 vf = *(const s16x8*)&Vt[(nf * 16 + l15) * 72 + ks * 32 + lg * 8];
          O[nf] = mfma_bf16(pfr, vf, O[nf]);
        }
      }
      __builtin_amdgcn_s_setprio(0);

      __syncthreads();
      if (pf) {
#pragma unroll
        for (int p = 0; p < 4; p++) {
          const int e = p * 128 + tid;
          *(s16x8*)&Kl[(e >> 3) * 72 + ((e & 7) << 3)] = kn[p];
          *(s16x8*)&Vt[(e >> 3) * 72 + ((e & 7) << 3)] = vn[p];
        }
        __syncthreads();
      }
    }

#pragma unroll
    for (int nf = 0; nf < 4; nf++)
#pragma unroll
      for (int r = 0; r < 4; r++) {
        const int row = q0 + w * 16 + lg * 4 + r;
        op[(size_t)row * 1024 + h * 64 + nf * 16 + l15] = f2bf(O[nf][r] / l_run[r]);
      }
  }
}

// ---------------- Plucker lines ----------------

__device__ __forceinline__ void exterior6(const float p1[4], const float p2[4], float L[6]) {
  L[0] = p1[0] * p2[1] - p1[1] * p2[0];
  L[1] = p1[0] * p2[2] - p1[2] * p2[0];
  L[2] = p1[0] * p2[3] - p1[3] * p2[0];
  L[3] = p1[1] * p2[2] - p1[2] * p2[1];
  L[4] = p1[1] * p2[3] - p1[3] * p2[1];
  L[5] = p1[2] * p2[3] - p1[3] * p2[2];
  float n = sqrtf(L[0] * L[0] + L[1] * L[1] + L[2] * L[2] +
                  L[3] * L[3] + L[4] * L[4] + L[5] * L[5]);
  float inv = 1.f / fmaxf(n, 1e-12f);
#pragma unroll
  for (int j = 0; j < 6; j++) L[j] *= inv;
}

// jw layout: SoA [bh][6][1024]; rl layout: AoS [bh][t][6]
__global__ void k_lines(const float* __restrict__ proj, const float* __restrict__ Jm,
                        float* __restrict__ jw, float* __restrict__ rl) {
  const int idx = blockIdx.x * 256 + threadIdx.x;  // 32768
  const int t = idx & 1023, h = (idx >> 10) & 15, b = idx >> 14;
  const int n = b * 1024 + t;
  const int bh = b * 16 + h;
  float p1[4], p2[4], L[6];
#pragma unroll
  for (int p = 0; p < 4; p++) {
    float a  = (t >= 2) ? proj[(size_t)(n - 2) * 384 + h * 4 + p] : 0.f;
    float bb = (t >= 1) ? proj[(size_t)(n - 1) * 384 + 64 + h * 4 + p] : 0.f;
    p1[p] = a + bb;
    p2[p] = proj[(size_t)n * 384 + 128 + h * 4 + p];
  }
  exterior6(p1, p2, L);
  const size_t jo = (size_t)bh * 6144 + t;
#pragma unroll
  for (int j = 0; j < 6; j++) {
    float s = 0.f;
#pragma unroll
    for (int i = 0; i < 6; i++) s += L[i] * Jm[i * 6 + j];
    jw[jo + (size_t)j * 1024] = s;
  }
#pragma unroll
  for (int p = 0; p < 4; p++) {
    p1[p] = proj[(size_t)n * 384 + 192 + h * 4 + p];
    p2[p] = proj[(size_t)n * 384 + 256 + h * 4 + p];
  }
  exterior6(p1, p2, L);
  const size_t ro = ((size_t)bh * 1024 + t) * 6;
#pragma unroll
  for (int j = 0; j < 6; j++) rl[ro + j] = L[j];
}

// ---------------- decayed memory score ----------------

__global__ __launch_bounds__(256) void k_mscore(const float* __restrict__ jw,
                                                const float* __restrict__ rl,
                                                const float* __restrict__ dlog,
                                                float* __restrict__ ms) {
  const int gtid = blockIdx.x * 256 + threadIdx.x;
  const int wid = gtid >> 6, lane = gtid & 63;
  const int bh = wid >> 10, t = wid & 1023;
  const int h = bh & 15, b = bh >> 4;
  const float d = 1.f / (1.f + expf(-dlog[h]));
  const float l2d = log2f(d);
  const float* jwp = jw + (size_t)bh * 6144;
  const float* rp = rl + ((size_t)bh * 1024 + t) * 6;
  const float r0 = rp[0], r1 = rp[1], r2 = rp[2], r3 = rp[3], r4 = rp[4], r5 = rp[5];
  float wgt = exp2f((float)(t - lane) * l2d);
  const float gw = exp2f(-64.f * l2d);
  float acc = 0.f;
  for (int s = lane; s < t; s += 64) {
    const float dot = r0 * jwp[s] + r1 * jwp[1024 + s] + r2 * jwp[2048 + s] +
                      r3 * jwp[3072 + s] + r4 * jwp[4096 + s] + r5 * jwp[5120 + s];
    acc += wgt * dot * dot;
    wgt *= gw;
  }
  acc += __shfl_xor(acc, 1, 64);
  acc += __shfl_xor(acc, 2, 64);
  acc += __shfl_xor(acc, 4, 64);
  acc += __shfl_xor(acc, 8, 64);
  acc += __shfl_xor(acc, 16, 64);
  acc += __shfl_xor(acc, 32, 64);
  if (lane == 0) ms[((size_t)(b * 1024 + t)) * 16 + h] = acc;
}

// ---------------- combine: comb = bf16(attn + gated*mem_val) ----------------

__global__ __launch_bounds__(256) void k_combine(const short* __restrict__ attn,
                                                 const short* __restrict__ fused,
                                                 const float* __restrict__ proj,
                                                 const float* __restrict__ ms,
                                                 const float* __restrict__ mem_scale,
                                                 const float* __restrict__ gate_b,
                                                 short* __restrict__ comb) {
  const int n = blockIdx.x;
  const int tid = threadIdx.x;
  __shared__ float gsh;
  if (tid < 16) {
    const float gp = proj[(size_t)n * 384 + 320 + tid] + gate_b[tid];
    const float g = 1.f / (1.f + expf(-gp));
    const float sc = ms[(size_t)n * 16 + tid] * mem_scale[tid];
    const float sg = 1.f / (1.f + expf(-sc));
    float v = sg * g;
    v += __shfl_xor(v, 1, 64);
    v += __shfl_xor(v, 2, 64);
    v += __shfl_xor(v, 4, 64);
    v += __shfl_xor(v, 8, 64);
    if (tid == 0) gsh = v * (1.f / 16.f);
  }
  __syncthreads();
  const float g = gsh;
  const int c0 = tid * 4;
  short4 av = *(const short4*)&attn[(size_t)n * 1024 + c0];
  short4 mvv = *(const short4*)&fused[(size_t)n * 4480 + 3072 + c0];
  short4 ov;
  ov.x = f2bf(bf2f(av.x) + g * bf2f(mvv.x));
  ov.y = f2bf(bf2f(av.y) + g * bf2f(mvv.y));
  ov.z = f2bf(bf2f(av.z) + g * bf2f(mvv.z));
  ov.w = f2bf(bf2f(av.w) + g * bf2f(mvv.w));
  *(short4*)&comb[(size_t)n * 1024 + c0] = ov;
}

// ---------------------------------------------------------------------------

extern "C" void kernel_launch(void* const* d_in, const int* in_sizes, int n_in,
                              void* d_out, int out_size, void* d_ws, size_t ws_size,
                              hipStream_t stream) {
  const float* x    = (const float*)d_in[0];
  const float* qkvw = (const float*)d_in[1];
  const float* qkvb = (const float*)d_in[2];
  const float* w1w  = (const float*)d_in[3];
  const float* w2w  = (const float*)d_in[4];
  const float* r1w  = (const float*)d_in[5];
  const float* r2w  = (const float*)d_in[6];
  const float* mvw  = (const float*)d_in[7];
  const float* mvb  = (const float*)d_in[8];
  const float* gw   = (const float*)d_in[9];
  const float* gb   = (const float*)d_in[10];
  const float* msc  = (const float*)d_in[11];
  const float* ow   = (const float*)d_in[12];
  const float* ob   = (const float*)d_in[13];
  const float* dlog = (const float*)d_in[14];
  const float* Jm   = (const float*)d_in[15];
  float* out = (float*)d_out;

  char* wsp = (char*)d_ws;
  auto alloc = [&](size_t bytes) {
    char* p = wsp;
    wsp += (bytes + 255) & ~(size_t)255;
    return p;
  };
  short* xb     = (short*)alloc((size_t)2048 * 1024 * 2);
  short* btall  = (short*)alloc((size_t)4480 * 1024 * 2);
  short* owT    = (short*)alloc((size_t)1024 * 1024 * 2);
  short* fusedC = (short*)alloc((size_t)2048 * 4480 * 2);
  float* projf  = (float*)alloc((size_t)2048 * 384 * 4);
  float* biasA  = (float*)alloc((size_t)4480 * 4);
  short* vtg    = (short*)alloc((size_t)32 * 64 * 1024 * 2);
  short* attnO  = (short*)alloc((size_t)2048 * 1024 * 2);
  short* comb   = (short*)alloc((size_t)2048 * 1024 * 2);
  float* jwb    = (float*)alloc((size_t)32 * 6144 * 4);
  float* rlb    = (float*)alloc((size_t)32768 * 6 * 4);
  float* msb    = (float*)alloc((size_t)2048 * 16 * 4);

  k_cvt<<<2048, 256, 0, stream>>>(x, xb, 2048 * 1024);
  dim3 tb(32, 8);
  k_tconv<<<dim3(96, 32), tb, 0, stream>>>(qkvw, btall, 1024, 3072);
  k_tconv<<<dim3(32, 32), tb, 0, stream>>>(mvw, btall + (size_t)3072 * 1024, 1024, 1024);
  k_tconv<<<dim3(32, 32), tb, 0, stream>>>(ow, owT, 1024, 1024);
  k_smallw<<<1554, 256, 0, stream>>>(w1w, w2w, r1w, r2w, gw, qkvb, mvb,
                                     btall + (size_t)4096 * 1024, biasA);

  k_gemmF<<<dim3(16, 35), 256, 0, stream>>>(xb, btall, fusedC, biasA, projf);

  k_vtr<<<dim3(32, 2, 32), tb, 0, stream>>>(fusedC, vtg);
  k_attn<<<512, 128, 0, stream>>>(fusedC, vtg, attnO);

  k_lines<<<128, 256, 0, stream>>>(projf, Jm, jwb, rlb);
  k_mscore<<<8192, 256, 0, stream>>>(jwb, rlb, dlog, msb);
  k_combine<<<2048, 256, 0, stream>>>(attnO, fusedC, projf, msb, msc, gb, comb);

  k_gemm<<<dim3(16, 8), 256, 0, stream>>>(comb, owT, out, ob, 1024, 1024);
}